// Round 1
// baseline (20694.275 us; speedup 1.0000x reference)
//
#include <hip/hip_runtime.h>
#include <hip/hip_fp16.h>

typedef _Float16 f16;
typedef _Float16 f16x2 __attribute__((ext_vector_type(2)));
typedef _Float16 f16x8 __attribute__((ext_vector_type(8)));
typedef float    f32x4 __attribute__((ext_vector_type(4)));

#define IN1 2048
#define H1  256
#define H2  128
#define BB  64
#define TT  512

// ---------------- workspace layout (bytes) ----------------
#define OFF_XF16   0ull
#define SZ_XF16    ((size_t)BB*TT*IN1*2)        // 134,217,728
#define OFF_WIH1   (OFF_XF16 + SZ_XF16)
#define SZ_WIH1    ((size_t)4*H1*IN1*2)         // 4,194,304
#define OFF_WHH1   (OFF_WIH1 + SZ_WIH1)
#define SZ_WHH1    ((size_t)4*H1*H1*2)          // 524,288
#define OFF_WIH2   (OFF_WHH1 + SZ_WHH1)
#define SZ_WIH2    ((size_t)4*H2*H1*2)          // 262,144
#define OFF_WHH2   (OFF_WIH2 + SZ_WIH2)
#define SZ_WHH2    ((size_t)4*H2*H2*2)          // 131,072
#define OFF_XG1    (OFF_WHH2 + SZ_WHH2)
#define SZ_XG1     ((size_t)BB*TT*4*H1*2)       // 67,108,864 (fp16)
#define OFF_XG2    (OFF_XG1 + SZ_XG1)
#define SZ_XG2     ((size_t)BB*TT*4*H2*2)       // 33,554,432 (fp16)
#define OFF_H1A    (OFF_XG2 + SZ_XG2)
#define SZ_H1A     ((size_t)BB*TT*H1*2)         // 16,777,216 (fp16)
#define OFF_GATES  (OFF_H1A + SZ_H1A)
#define SZ_GATES   ((size_t)BB*2*4*H1*4)        // 524,288 (fp32, double-buffered)
#define OFF_CTR    (OFF_GATES + SZ_GATES)       // 64 counters + pad

// ---------------- helpers ----------------
__device__ __forceinline__ float sigm(float x){ return 1.f/(1.f + __expf(-x)); }
__device__ __forceinline__ float tanh_(float x){ return 1.f - 2.f/(__expf(2.f*x) + 1.f); }

__device__ __forceinline__ float dot2f(unsigned a, unsigned b, float c){
  f16x2 ah = __builtin_bit_cast(f16x2, a);
  f16x2 bh = __builtin_bit_cast(f16x2, b);
#if defined(__has_builtin)
#if __has_builtin(__builtin_amdgcn_fdot2)
  return __builtin_amdgcn_fdot2(ah, bh, c, false);
#else
  return c + (float)ah[0]*(float)bh[0] + (float)ah[1]*(float)bh[1];
#endif
#else
  return c + (float)ah[0]*(float)bh[0] + (float)ah[1]*(float)bh[1];
#endif
}

// ---------------- fp32 -> fp16 convert ----------------
__global__ void cvt_f32_f16(const float* __restrict__ in, f16* __restrict__ out, int n4){
  int i = blockIdx.x*blockDim.x + threadIdx.x;
  int st = gridDim.x*blockDim.x;
  for (; i < n4; i += st){
    float4 v = ((const float4*)in)[i];
    f16x2 p0; p0[0] = (f16)v.x; p0[1] = (f16)v.y;
    f16x2 p1; p1[0] = (f16)v.z; p1[1] = (f16)v.w;
    ((f16x2*)out)[2*i]   = p0;
    ((f16x2*)out)[2*i+1] = p1;
  }
}

// ---------------- fp16 MFMA GEMM, C = A * Bt^T + bias (B^T layout) ----------------
// A: (M,K) row-major fp16.  Bt: (N,K) row-major fp16.  C: (M,N) fp16.
// BM=BN=128, BK=32, 256 threads (4 waves, 2x2 wave grid, each wave 64x64).
template<int K, int N>
__global__ __launch_bounds__(256,1)
void gemm_bt(const f16* __restrict__ A, const f16* __restrict__ Bt,
             const float* __restrict__ b1, const float* __restrict__ b2,
             f16* __restrict__ C){
  __shared__ f16 As[128*32];
  __shared__ f16 Bs[128*32];
  const int tid  = threadIdx.x;
  const int m0   = blockIdx.y*128, n0 = blockIdx.x*128;
  const int wave = tid>>6, lane = tid&63;
  const int wm = wave>>1, wn = wave&1;
  const int lr = lane&15, lk = lane>>4;
  f32x4 acc[4][4] = {};
  for (int kt = 0; kt < K; kt += 32){
    #pragma unroll
    for (int i = 0; i < 2; i++){
      int f = tid*16 + i*8;
      int r = f>>5, c = f&31;
      *(uint4*)&As[f] = *(const uint4*)&A[(size_t)(m0+r)*K + kt + c];
      *(uint4*)&Bs[f] = *(const uint4*)&Bt[(size_t)(n0+r)*K + kt + c];
    }
    __syncthreads();
    f16x8 av[4], bv[4];
    #pragma unroll
    for (int mi = 0; mi < 4; mi++)
      av[mi] = *(const f16x8*)&As[(wm*64 + mi*16 + lr)*32 + lk*8];
    #pragma unroll
    for (int ni = 0; ni < 4; ni++)
      bv[ni] = *(const f16x8*)&Bs[(wn*64 + ni*16 + lr)*32 + lk*8];
    #pragma unroll
    for (int mi = 0; mi < 4; mi++)
      #pragma unroll
      for (int ni = 0; ni < 4; ni++)
        acc[mi][ni] = __builtin_amdgcn_mfma_f32_16x16x32_f16(av[mi], bv[ni], acc[mi][ni], 0, 0, 0);
    __syncthreads();
  }
  // epilogue: D frag mapping col = lane&15 (n), row = (lane>>4)*4 + j (m)
  #pragma unroll
  for (int ni = 0; ni < 4; ni++){
    int n = n0 + wn*64 + ni*16 + lr;
    float bb = b1[n] + b2[n];
    #pragma unroll
    for (int mi = 0; mi < 4; mi++){
      int mbase = m0 + wm*64 + mi*16 + lk*4;
      #pragma unroll
      for (int j = 0; j < 4; j++)
        C[(size_t)(mbase + j)*N + n] = (f16)(acc[mi][ni][j] + bb);
    }
  }
}

// ---------------- layer-1 recurrence: 4 WGs per batch, register-resident Whh1 slice ----------------
// grid = 256 blocks x 512 threads. block i -> batch=(i%8)*8+(i/8)/4 (XCD co-location heuristic), q=(i/8)%4.
// Thread t: gate row r=t&255 (global row q*256+r), K-half kh=t>>8 (k in [128*kh,128*kh+128)).
__global__ __launch_bounds__(512,1)
void lstm1_kernel(const f16* __restrict__ xg1, const f16* __restrict__ Whh,
                  f16* __restrict__ h1a, float* __restrict__ gates,
                  unsigned* __restrict__ ctr){
  const int t   = threadIdx.x;
  const int blk = blockIdx.x;
  const int xcd = blk & 7, sub = blk >> 3;
  const int batch = xcd*8 + (sub>>2);
  const int q     = sub & 3;
  const int r  = t & 255, kh = t >> 8;

  uint4 w[16];
  {
    const uint4* wp = (const uint4*)(Whh + ((size_t)(q*256 + r))*256 + kh*128);
    #pragma unroll
    for (int i = 0; i < 16; i++) w[i] = wp[i];
  }

  __shared__ __align__(16) f16x2 h1s[128];   // packed fp16 h (256 values)
  __shared__ float c1[256];
  __shared__ float part[512];
  __shared__ float xgb[256];

  if (t < 256) c1[t] = 0.f;
  if (t < 128){ f16x2 z = {}; h1s[t] = z; }
  __syncthreads();

  for (int ts = 0; ts < TT; ++ts){
    // prefetch this step's xg slice (fp16 -> fp32 LDS)
    if (t < 128){
      unsigned v = *(const unsigned*)(xg1 + (size_t)(batch*TT + ts)*1024 + q*256 + t*2);
      f16x2 hv = __builtin_bit_cast(f16x2, v);
      xgb[t*2]   = (float)hv[0];
      xgb[t*2+1] = (float)hv[1];
    }
    // partial dot: Whh[G, kh*128 : kh*128+128] . h[kh*128 : ...]
    float a0 = 0.f, a1 = 0.f, a2 = 0.f, a3 = 0.f;
    const uint4* hp = (const uint4*)(h1s + kh*64);
    #pragma unroll
    for (int i = 0; i < 16; i++){
      uint4 hv = hp[i];
      a0 = dot2f(w[i].x, hv.x, a0);
      a1 = dot2f(w[i].y, hv.y, a1);
      a2 = dot2f(w[i].z, hv.z, a2);
      a3 = dot2f(w[i].w, hv.w, a3);
    }
    part[t] = (a0 + a1) + (a2 + a3);
    __syncthreads();

    float* gbuf = gates + ((size_t)batch*2 + (ts & 1))*1024;
    if (t < 256){
      float gp = part[t] + part[t + 256] + xgb[t];
      gbuf[q*256 + t] = gp;
    }
    __threadfence();
    __syncthreads();
    if (t == 0){
      __hip_atomic_fetch_add(&ctr[batch], 1u, __ATOMIC_RELEASE, __HIP_MEMORY_SCOPE_AGENT);
      unsigned tg = 4u*(unsigned)(ts + 1);
      while (__hip_atomic_load(&ctr[batch], __ATOMIC_ACQUIRE, __HIP_MEMORY_SCOPE_AGENT) < tg)
        __builtin_amdgcn_s_sleep(1);
    }
    __syncthreads();

    // replicated cell update (identical in all 4 WGs)
    if (t < 256){
      float gi = gbuf[t], gf = gbuf[256 + t], gg = gbuf[512 + t], go = gbuf[768 + t];
      float c = sigm(gf)*c1[t] + sigm(gi)*tanh_(gg);
      c1[t] = c;
      float h = sigm(go)*tanh_(c);
      f16 hh = (f16)h;
      ((f16*)h1s)[t] = hh;
      if (q == 0) h1a[(size_t)(batch*TT + ts)*H1 + t] = hh;
    }
    __syncthreads();
  }
}

// ---------------- layer-2 recurrence + head: 1 WG per batch, register-resident Whh2 ----------------
__global__ __launch_bounds__(512,1)
void lstm2_kernel(const f16* __restrict__ xg2, const f16* __restrict__ Whh,
                  const float* __restrict__ Wfc, const float* __restrict__ bfc,
                  const float* __restrict__ Wo,  const float* __restrict__ bo,
                  float* __restrict__ out){
  const int t = threadIdx.x, b = blockIdx.x;

  uint4 w[16];
  {
    const uint4* wp = (const uint4*)(Whh + (size_t)t*H2);
    #pragma unroll
    for (int i = 0; i < 16; i++) w[i] = wp[i];
  }

  __shared__ __align__(16) f16x2 h2s[64];    // packed fp16 h2 (128)
  __shared__ float c2[128];
  __shared__ float h2f[128];
  __shared__ float gb[512];
  __shared__ float fc[64];

  if (t < 128){ c2[t] = 0.f; h2f[t] = 0.f; }
  if (t < 64){ f16x2 z = {}; h2s[t] = z; }
  __syncthreads();

  for (int ts = 0; ts < TT; ++ts){
    float xv = (float)xg2[(size_t)(b*TT + ts)*512 + t];
    float a0 = 0.f, a1 = 0.f, a2 = 0.f, a3 = 0.f;
    const uint4* hp = (const uint4*)h2s;
    #pragma unroll
    for (int i = 0; i < 16; i++){
      uint4 hv = hp[i];
      a0 = dot2f(w[i].x, hv.x, a0);
      a1 = dot2f(w[i].y, hv.y, a1);
      a2 = dot2f(w[i].z, hv.z, a2);
      a3 = dot2f(w[i].w, hv.w, a3);
    }
    gb[t] = xv + (a0 + a1) + (a2 + a3);
    __syncthreads();
    if (t < 128){
      float gi = gb[t], gf = gb[128 + t], gg = gb[256 + t], go = gb[384 + t];
      float c = sigm(gf)*c2[t] + sigm(gi)*tanh_(gg);
      c2[t] = c;
      float h = sigm(go)*tanh_(c);
      h2f[t] = h;
      ((f16*)h2s)[t] = (f16)h;
    }
    __syncthreads();
  }

  // head: fc1 = relu(W_fc1 @ h2 + b_fc1); out = W_out @ fc1 + b_out
  if (t < 64){
    float s = bfc[t];
    #pragma unroll 4
    for (int j = 0; j < 128; j++) s += Wfc[t*128 + j]*h2f[j];
    fc[t] = fmaxf(s, 0.f);
  }
  __syncthreads();
  if (t == 0){
    float s = bo[0];
    #pragma unroll 4
    for (int k = 0; k < 64; k++) s += Wo[k]*fc[k];
    out[b] = s;
  }
}

// ---------------- launch ----------------
extern "C" void kernel_launch(void* const* d_in, const int* in_sizes, int n_in,
                              void* d_out, int out_size, void* d_ws, size_t ws_size,
                              hipStream_t stream){
  const float* x    = (const float*)d_in[0];
  const float* Wih1 = (const float*)d_in[1];
  const float* Whh1 = (const float*)d_in[2];
  const float* bih1 = (const float*)d_in[3];
  const float* bhh1 = (const float*)d_in[4];
  const float* Wih2 = (const float*)d_in[5];
  const float* Whh2 = (const float*)d_in[6];
  const float* bih2 = (const float*)d_in[7];
  const float* bhh2 = (const float*)d_in[8];
  const float* Wfc  = (const float*)d_in[9];
  const float* bfc  = (const float*)d_in[10];
  const float* Wo   = (const float*)d_in[11];
  const float* bo   = (const float*)d_in[12];

  char* ws = (char*)d_ws;
  f16* xf    = (f16*)(ws + OFF_XF16);
  f16* wih1f = (f16*)(ws + OFF_WIH1);
  f16* whh1f = (f16*)(ws + OFF_WHH1);
  f16* wih2f = (f16*)(ws + OFF_WIH2);
  f16* whh2f = (f16*)(ws + OFF_WHH2);
  f16* xg1   = (f16*)(ws + OFF_XG1);
  f16* xg2   = (f16*)(ws + OFF_XG2);
  f16* h1a   = (f16*)(ws + OFF_H1A);
  float* gatesb = (float*)(ws + OFF_GATES);
  unsigned* ctr = (unsigned*)(ws + OFF_CTR);

  hipMemsetAsync(ctr, 0, 256, stream);

  cvt_f32_f16<<<4096, 256, 0, stream>>>(x,    xf,    BB*TT*IN1/4);
  cvt_f32_f16<<<512,  256, 0, stream>>>(Wih1, wih1f, 4*H1*IN1/4);
  cvt_f32_f16<<<64,   256, 0, stream>>>(Whh1, whh1f, 4*H1*H1/4);
  cvt_f32_f16<<<32,   256, 0, stream>>>(Wih2, wih2f, 4*H2*H1/4);
  cvt_f32_f16<<<16,   256, 0, stream>>>(Whh2, whh2f, 4*H2*H2/4);

  // xg1 = x @ Wih1^T + (bih1 + bhh1):  M=32768, N=1024, K=2048
  gemm_bt<IN1, 4*H1><<<dim3(8, 256), 256, 0, stream>>>(xf, wih1f, bih1, bhh1, xg1);

  // layer-1 recurrence (4 WGs per batch, device-scope barrier)
  lstm1_kernel<<<256, 512, 0, stream>>>(xg1, whh1f, h1a, gatesb, ctr);

  // xg2 = h1 @ Wih2^T + (bih2 + bhh2):  M=32768, N=512, K=256
  gemm_bt<H1, 4*H2><<<dim3(4, 256), 256, 0, stream>>>(h1a, wih2f, bih2, bhh2, xg2);

  // layer-2 recurrence + FC head
  lstm2_kernel<<<64, 512, 0, stream>>>(xg2, whh2f, Wfc, bfc, Wo, bo, (float*)d_out);
}

// Round 2
// 2174.777 us; speedup vs baseline: 9.5156x; 9.5156x over previous
//
#include <hip/hip_runtime.h>
#include <hip/hip_fp16.h>

typedef _Float16 f16;
typedef _Float16 f16x2 __attribute__((ext_vector_type(2)));
typedef _Float16 f16x8 __attribute__((ext_vector_type(8)));
typedef float    f32x4 __attribute__((ext_vector_type(4)));

#define IN1 2048
#define H1  256
#define H2  128
#define BB  64
#define TT  512

// ---------------- workspace layout (bytes) ----------------
#define OFF_XF16   0ull
#define SZ_XF16    ((size_t)BB*TT*IN1*2)        // 134,217,728
#define OFF_WIH1   (OFF_XF16 + SZ_XF16)
#define SZ_WIH1    ((size_t)4*H1*IN1*2)         // 4,194,304
#define OFF_WHH1   (OFF_WIH1 + SZ_WIH1)
#define SZ_WHH1    ((size_t)4*H1*H1*2)          // 524,288
#define OFF_WIH2   (OFF_WHH1 + SZ_WHH1)
#define SZ_WIH2    ((size_t)4*H2*H1*2)          // 262,144
#define OFF_WHH2   (OFF_WIH2 + SZ_WIH2)
#define SZ_WHH2    ((size_t)4*H2*H2*2)          // 131,072
#define OFF_XG1    (OFF_WHH2 + SZ_WHH2)
#define SZ_XG1     ((size_t)BB*TT*4*H1*2)       // 67,108,864 (fp16)
#define OFF_XG2    (OFF_XG1 + SZ_XG1)
#define SZ_XG2     ((size_t)BB*TT*4*H2*2)       // 33,554,432 (fp16)
#define OFF_H1A    (OFF_XG2 + SZ_XG2)
#define SZ_H1A     ((size_t)BB*TT*H1*2)         // 16,777,216 (fp16)
#define OFF_HX     (OFF_H1A + SZ_H1A)
#define SZ_HX      ((size_t)2*BB*H1*2)          // 65,536 (double-buffered h exchange, fp16)
#define OFF_FLG    (OFF_HX + SZ_HX)
#define SZ_FLG     ((size_t)BB*4*64*4)          // 65,536 (1 flag per 256B line)

// ---------------- helpers ----------------
__device__ __forceinline__ float sigm(float x){ return 1.f/(1.f + __expf(-x)); }
__device__ __forceinline__ float tanh_(float x){ return 1.f - 2.f/(__expf(2.f*x) + 1.f); }

__device__ __forceinline__ float dot2f(unsigned a, unsigned b, float c){
  f16x2 ah = __builtin_bit_cast(f16x2, a);
  f16x2 bh = __builtin_bit_cast(f16x2, b);
#if defined(__has_builtin)
#if __has_builtin(__builtin_amdgcn_fdot2)
  return __builtin_amdgcn_fdot2(ah, bh, c, false);
#else
  return c + (float)ah[0]*(float)bh[0] + (float)ah[1]*(float)bh[1];
#endif
#else
  return c + (float)ah[0]*(float)bh[0] + (float)ah[1]*(float)bh[1];
#endif
}

// ---------------- fp32 -> fp16 convert ----------------
__global__ void cvt_f32_f16(const float* __restrict__ in, f16* __restrict__ out, int n4){
  int i = blockIdx.x*blockDim.x + threadIdx.x;
  int st = gridDim.x*blockDim.x;
  for (; i < n4; i += st){
    float4 v = ((const float4*)in)[i];
    f16x2 p0; p0[0] = (f16)v.x; p0[1] = (f16)v.y;
    f16x2 p1; p1[0] = (f16)v.z; p1[1] = (f16)v.w;
    ((f16x2*)out)[2*i]   = p0;
    ((f16x2*)out)[2*i+1] = p1;
  }
}

// ---------------- fp16 MFMA GEMM, C = A * Bt^T + bias (B^T layout) ----------------
template<int K, int N>
__global__ __launch_bounds__(256,1)
void gemm_bt(const f16* __restrict__ A, const f16* __restrict__ Bt,
             const float* __restrict__ b1, const float* __restrict__ b2,
             f16* __restrict__ C){
  __shared__ f16 As[128*32];
  __shared__ f16 Bs[128*32];
  const int tid  = threadIdx.x;
  const int m0   = blockIdx.y*128, n0 = blockIdx.x*128;
  const int wave = tid>>6, lane = tid&63;
  const int wm = wave>>1, wn = wave&1;
  const int lr = lane&15, lk = lane>>4;
  f32x4 acc[4][4] = {};
  for (int kt = 0; kt < K; kt += 32){
    #pragma unroll
    for (int i = 0; i < 2; i++){
      int f = tid*16 + i*8;
      int r = f>>5, c = f&31;
      *(uint4*)&As[f] = *(const uint4*)&A[(size_t)(m0+r)*K + kt + c];
      *(uint4*)&Bs[f] = *(const uint4*)&Bt[(size_t)(n0+r)*K + kt + c];
    }
    __syncthreads();
    f16x8 av[4], bv[4];
    #pragma unroll
    for (int mi = 0; mi < 4; mi++)
      av[mi] = *(const f16x8*)&As[(wm*64 + mi*16 + lr)*32 + lk*8];
    #pragma unroll
    for (int ni = 0; ni < 4; ni++)
      bv[ni] = *(const f16x8*)&Bs[(wn*64 + ni*16 + lr)*32 + lk*8];
    #pragma unroll
    for (int mi = 0; mi < 4; mi++)
      #pragma unroll
      for (int ni = 0; ni < 4; ni++)
        acc[mi][ni] = __builtin_amdgcn_mfma_f32_16x16x32_f16(av[mi], bv[ni], acc[mi][ni], 0, 0, 0);
    __syncthreads();
  }
  #pragma unroll
  for (int ni = 0; ni < 4; ni++){
    int n = n0 + wn*64 + ni*16 + lr;
    float bb = b1[n] + b2[n];
    #pragma unroll
    for (int mi = 0; mi < 4; mi++){
      int mbase = m0 + wm*64 + mi*16 + lk*4;
      #pragma unroll
      for (int j = 0; j < 4; j++)
        C[(size_t)(mbase + j)*N + n] = (f16)(acc[mi][ni][j] + bb);
    }
  }
}

// ---------------- layer-1 recurrence: 4 WGs per batch, SPLIT BY HIDDEN UNIT ----------------
// WG (q,b) at blk = q*64 + b owns units [q*64, q*64+64): all 4 gate rows for those units.
// Weights register-resident (64 VGPR/thread). Cell update is WG-local; only the 64
// fp16 h-values cross WGs per step, via a fence-free sc1 mailbox + per-WG padded flag.
// Thread t: ul=t&63 (local unit), g=(t>>6)&3 (gate), kh=t>>8 (K-half).
__global__ __launch_bounds__(512,1)
void lstm1_kernel(const f16* __restrict__ xg1, const f16* __restrict__ Whh,
                  f16* __restrict__ h1a, unsigned* __restrict__ hx,
                  unsigned* __restrict__ flg){
  const int t   = threadIdx.x;
  const int blk = blockIdx.x;
  const int q = blk >> 6, b = blk & 63;
  const int ul = t & 63, g = (t >> 6) & 3, kh = t >> 8;

  uint4 w[16];
  {
    const uint4* wp = (const uint4*)(Whh + ((size_t)(g*256 + q*64 + ul))*256 + kh*128);
    #pragma unroll
    for (int i = 0; i < 16; i++) w[i] = wp[i];
  }

  __shared__ __align__(16) f16 hfull[256];
  __shared__ float part[512];

  if (t < 128) ((f16x2*)hfull)[t] = f16x2{};
  __syncthreads();

  float creg = 0.f;                         // cell state, valid for t<64 (unit q*64+t)
  float xgc = 0.f;
  if (t < 256)
    xgc = (float)xg1[(size_t)b*512*1024 + g*256 + q*64 + ul];

  for (int ts = 0; ts < TT; ++ts){
    // prefetch next step's xg slice (overlaps with matmul)
    float xgn = 0.f;
    if (t < 256){
      int tn = ts + 1 < 512 ? ts + 1 : 511;
      xgn = (float)xg1[((size_t)b*512 + tn)*1024 + g*256 + q*64 + ul];
    }
    // partial dot: W[g*256+q*64+ul, kh*128 : kh*128+128] . h[kh*128 : ...]
    float a0 = 0.f, a1 = 0.f, a2 = 0.f, a3 = 0.f;
    const uint4* hp = ((const uint4*)hfull) + kh*16;
    #pragma unroll
    for (int i = 0; i < 16; i++){
      uint4 hv = hp[i];
      a0 = dot2f(w[i].x, hv.x, a0);
      a1 = dot2f(w[i].y, hv.y, a1);
      a2 = dot2f(w[i].z, hv.z, a2);
      a3 = dot2f(w[i].w, hv.w, a3);
    }
    part[t] = (a0 + a1) + (a2 + a3);
    __syncthreads();
    if (t < 256) part[t] = part[t] + part[t + 256] + xgc;   // gate preact, idx g*64+ul
    __syncthreads();
    if (t < 64){
      float gi = part[t], gf = part[64 + t], gg = part[128 + t], go = part[192 + t];
      float c = sigm(gf)*creg + sigm(gi)*tanh_(gg);
      creg = c;
      float h = sigm(go)*tanh_(c);
      f16 hh = (f16)h;
      hfull[q*64 + t] = hh;
      h1a[((size_t)b*512 + ts)*256 + q*64 + t] = hh;
    }
    __syncthreads();                       // own h slice in LDS, stores drained

    if (ts < 511){
      // wave 0 publishes: 32 packed sc1 stores -> vmcnt(0) -> flag store (own 256B line)
      if (t < 32){
        unsigned v = ((const unsigned*)hfull)[q*32 + t];
        __hip_atomic_store(&hx[((ts & 1)*64 + b)*128 + q*32 + t], v,
                           __ATOMIC_RELAXED, __HIP_MEMORY_SCOPE_AGENT);
      }
      if (t == 0){
        asm volatile("s_waitcnt vmcnt(0)" ::: "memory");
        __hip_atomic_store(&flg[(b*4 + q)*64], (unsigned)(ts + 1),
                           __ATOMIC_RELAXED, __HIP_MEMORY_SCOPE_AGENT);
      }
      // poll the 3 partners' flags (each on its own line; no RMW)
      if (t < 3){
        int pq = (q + 1 + t) & 3;
        const unsigned* fp = &flg[(b*4 + pq)*64];
        while (__hip_atomic_load(fp, __ATOMIC_RELAXED, __HIP_MEMORY_SCOPE_AGENT)
               <= (unsigned)ts)
          __builtin_amdgcn_s_sleep(1);
      }
      __syncthreads();
      // fetch partners' h slices
      if (t < 96){
        int pi = t >> 5, wl = t & 31;
        int pq = (q + 1 + pi) & 3;
        unsigned v = __hip_atomic_load(&hx[((ts & 1)*64 + b)*128 + pq*32 + wl],
                                       __ATOMIC_RELAXED, __HIP_MEMORY_SCOPE_AGENT);
        ((unsigned*)hfull)[pq*32 + wl] = v;
      }
      __syncthreads();
    }
    xgc = xgn;
  }
}

// ---------------- layer-2 recurrence + head: 1 WG per batch, register-resident Whh2 ----------------
__global__ __launch_bounds__(512,1)
void lstm2_kernel(const f16* __restrict__ xg2, const f16* __restrict__ Whh,
                  const float* __restrict__ Wfc, const float* __restrict__ bfc,
                  const float* __restrict__ Wo,  const float* __restrict__ bo,
                  float* __restrict__ out){
  const int t = threadIdx.x, b = blockIdx.x;

  uint4 w[16];
  {
    const uint4* wp = (const uint4*)(Whh + (size_t)t*H2);
    #pragma unroll
    for (int i = 0; i < 16; i++) w[i] = wp[i];
  }

  __shared__ __align__(16) f16x2 h2s[64];
  __shared__ float c2[128];
  __shared__ float h2f[128];
  __shared__ float gb[512];
  __shared__ float fc[64];

  if (t < 128){ c2[t] = 0.f; h2f[t] = 0.f; }
  if (t < 64){ f16x2 z = {}; h2s[t] = z; }
  __syncthreads();

  for (int ts = 0; ts < TT; ++ts){
    float xv = (float)xg2[(size_t)(b*TT + ts)*512 + t];
    float a0 = 0.f, a1 = 0.f, a2 = 0.f, a3 = 0.f;
    const uint4* hp = (const uint4*)h2s;
    #pragma unroll
    for (int i = 0; i < 16; i++){
      uint4 hv = hp[i];
      a0 = dot2f(w[i].x, hv.x, a0);
      a1 = dot2f(w[i].y, hv.y, a1);
      a2 = dot2f(w[i].z, hv.z, a2);
      a3 = dot2f(w[i].w, hv.w, a3);
    }
    gb[t] = xv + (a0 + a1) + (a2 + a3);
    __syncthreads();
    if (t < 128){
      float gi = gb[t], gf = gb[128 + t], gg = gb[256 + t], go = gb[384 + t];
      float c = sigm(gf)*c2[t] + sigm(gi)*tanh_(gg);
      c2[t] = c;
      float h = sigm(go)*tanh_(c);
      h2f[t] = h;
      ((f16*)h2s)[t] = (f16)h;
    }
    __syncthreads();
  }

  if (t < 64){
    float s = bfc[t];
    #pragma unroll 4
    for (int j = 0; j < 128; j++) s += Wfc[t*128 + j]*h2f[j];
    fc[t] = fmaxf(s, 0.f);
  }
  __syncthreads();
  if (t == 0){
    float s = bo[0];
    #pragma unroll 4
    for (int k = 0; k < 64; k++) s += Wo[k]*fc[k];
    out[b] = s;
  }
}

// ---------------- launch ----------------
extern "C" void kernel_launch(void* const* d_in, const int* in_sizes, int n_in,
                              void* d_out, int out_size, void* d_ws, size_t ws_size,
                              hipStream_t stream){
  const float* x    = (const float*)d_in[0];
  const float* Wih1 = (const float*)d_in[1];
  const float* Whh1 = (const float*)d_in[2];
  const float* bih1 = (const float*)d_in[3];
  const float* bhh1 = (const float*)d_in[4];
  const float* Wih2 = (const float*)d_in[5];
  const float* Whh2 = (const float*)d_in[6];
  const float* bih2 = (const float*)d_in[7];
  const float* bhh2 = (const float*)d_in[8];
  const float* Wfc  = (const float*)d_in[9];
  const float* bfc  = (const float*)d_in[10];
  const float* Wo   = (const float*)d_in[11];
  const float* bo   = (const float*)d_in[12];

  char* ws = (char*)d_ws;
  f16* xf    = (f16*)(ws + OFF_XF16);
  f16* wih1f = (f16*)(ws + OFF_WIH1);
  f16* whh1f = (f16*)(ws + OFF_WHH1);
  f16* wih2f = (f16*)(ws + OFF_WIH2);
  f16* whh2f = (f16*)(ws + OFF_WHH2);
  f16* xg1   = (f16*)(ws + OFF_XG1);
  f16* xg2   = (f16*)(ws + OFF_XG2);
  f16* h1a   = (f16*)(ws + OFF_H1A);
  unsigned* hx  = (unsigned*)(ws + OFF_HX);
  unsigned* flg = (unsigned*)(ws + OFF_FLG);

  hipMemsetAsync(flg, 0, SZ_FLG, stream);

  cvt_f32_f16<<<4096, 256, 0, stream>>>(x,    xf,    BB*TT*IN1/4);
  cvt_f32_f16<<<512,  256, 0, stream>>>(Wih1, wih1f, 4*H1*IN1/4);
  cvt_f32_f16<<<64,   256, 0, stream>>>(Whh1, whh1f, 4*H1*H1/4);
  cvt_f32_f16<<<32,   256, 0, stream>>>(Wih2, wih2f, 4*H2*H1/4);
  cvt_f32_f16<<<16,   256, 0, stream>>>(Whh2, whh2f, 4*H2*H2/4);

  // xg1 = x @ Wih1^T + (bih1 + bhh1):  M=32768, N=1024, K=2048
  gemm_bt<IN1, 4*H1><<<dim3(8, 256), 256, 0, stream>>>(xf, wih1f, bih1, bhh1, xg1);

  // layer-1 recurrence (4 WGs per batch, unit-split, mailbox exchange)
  lstm1_kernel<<<256, 512, 0, stream>>>(xg1, whh1f, h1a, hx, flg);

  // xg2 = h1 @ Wih2^T + (bih2 + bhh2):  M=32768, N=512, K=256
  gemm_bt<H1, 4*H2><<<dim3(4, 256), 256, 0, stream>>>(h1a, wih2f, bih2, bhh2, xg2);

  // layer-2 recurrence + FC head
  lstm2_kernel<<<64, 512, 0, stream>>>(xg2, whh2f, Wfc, bfc, Wo, bo, (float*)d_out);
}